// Round 4
// baseline (737.915 us; speedup 1.0000x reference)
//
#include <hip/hip_runtime.h>
#include <cstddef>

// Problem constants: B=4, S=2048, D=1024, H=16, HD=64
constexpr int Bn  = 4;
constexpr int Sn  = 2048;
constexpr int Dn  = 1024;
constexpr int Hn  = 16;
constexpr int HDn = 64;

typedef __bf16 bf16;
typedef __attribute__((ext_vector_type(8))) __bf16 bf16x8;
typedef __attribute__((ext_vector_type(4))) float  f32x4;

// ---------------------------------------------------------------------------
// Elementwise fp32 -> bf16 (x staging)
// ---------------------------------------------------------------------------
__global__ __launch_bounds__(256) void conv_f32_bf16_k(
    const float* __restrict__ in, bf16* __restrict__ out, int n)
{
    int i = (blockIdx.x * 256 + threadIdx.x) * 4;
    if (i + 3 < n) {
        float4 v = *(const float4*)(in + i);
        bf16 o[4] = {(bf16)v.x, (bf16)v.y, (bf16)v.z, (bf16)v.w};
        *(ulong1*)(out + i) = *(ulong1*)o;  // 8B store
    }
}

// ---------------------------------------------------------------------------
// Weight transpose + convert: W[k][n] fp32 -> Wt[n][k] bf16. 64x64 tiles.
// ---------------------------------------------------------------------------
__global__ __launch_bounds__(256) void conv_wt_k(
    const float* __restrict__ w0, const float* __restrict__ w1,
    const float* __restrict__ w2, const float* __restrict__ w3,
    bf16* __restrict__ o0, bf16* __restrict__ o1,
    bf16* __restrict__ o2, bf16* __restrict__ o3)
{
    const float* W = (blockIdx.z == 0) ? w0 : (blockIdx.z == 1) ? w1
                   : (blockIdx.z == 2) ? w2 : w3;
    bf16* O = (blockIdx.z == 0) ? o0 : (blockIdx.z == 1) ? o1
            : (blockIdx.z == 2) ? o2 : o3;
    __shared__ float t[64][65];
    const int tid = threadIdx.x;
    const int k0 = blockIdx.x * 64;
    const int n0 = blockIdx.y * 64;
    #pragma unroll
    for (int p = 0; p < 16; ++p) {
        const int idx = p * 256 + tid;
        const int r = idx >> 6, c = idx & 63;
        t[r][c] = W[(size_t)(k0 + r) * Dn + n0 + c];
    }
    __syncthreads();
    #pragma unroll
    for (int p = 0; p < 16; ++p) {
        const int idx = p * 256 + tid;
        const int r = idx >> 6, c = idx & 63;
        O[(size_t)(n0 + r) * Dn + k0 + c] = (bf16)t[c][r];
    }
}

// ---------------------------------------------------------------------------
// bf16 MFMA GEMM: out = A(8192 x 1024) @ Bt^T + bias, Bt is [N][K] bf16.
// Tile 128x64, 256 thr / 4 waves (2x2), each wave 64x32 (4x2 of 16x16 frags).
// BK=64. MFMA 16x16x32 bf16, fragment maps (verified R3):
//   A[m=lane&15][k=quad*8+j], B[k=quad*8+j][n=lane&15],
//   C/D: col=lane&15, row=quad*4+reg.
// MODE 0: fp32 out [M][N];  MODE 1: bf16 out [b,h,s,hd];  MODE 2: bf16 [b,h,hd,s]
// ---------------------------------------------------------------------------
template <int MODE>
__global__ __launch_bounds__(256) void gemm_bf16_k(
    const bf16* __restrict__ A, const bf16* __restrict__ Bt,
    const float* __restrict__ bias, void* __restrict__ outv)
{
    __shared__ __align__(16) bf16 As[128][72];
    __shared__ __align__(16) bf16 Bs[64][72];

    const int tid  = threadIdx.x;
    const int w    = tid >> 6;
    const int lane = tid & 63;
    const int quad = lane >> 4;
    const int l15  = lane & 15;
    const int wr   = (w & 1) * 64;     // wave row offset in tile
    const int wc   = (w >> 1) * 32;    // wave col offset in tile
    const int m0   = blockIdx.x * 128;
    const int n0   = blockIdx.y * 64;

    f32x4 acc[4][2] = {};

    for (int k0 = 0; k0 < Dn; k0 += 64) {
        #pragma unroll
        for (int p = 0; p < 4; ++p) {
            const int idx = p * 256 + tid;
            const int r = idx >> 3, off = (idx & 7) * 8;
            *(bf16x8*)&As[r][off] =
                *(const bf16x8*)(A + (size_t)(m0 + r) * Dn + k0 + off);
        }
        #pragma unroll
        for (int p = 0; p < 2; ++p) {
            const int idx = p * 256 + tid;
            const int r = idx >> 3, off = (idx & 7) * 8;
            *(bf16x8*)&Bs[r][off] =
                *(const bf16x8*)(Bt + (size_t)(n0 + r) * Dn + k0 + off);
        }
        __syncthreads();
        #pragma unroll
        for (int ks = 0; ks < 64; ks += 32) {
            bf16x8 af[4], bfr[2];
            #pragma unroll
            for (int mt = 0; mt < 4; ++mt)
                af[mt] = *(const bf16x8*)&As[wr + mt * 16 + l15][ks + quad * 8];
            #pragma unroll
            for (int nt = 0; nt < 2; ++nt)
                bfr[nt] = *(const bf16x8*)&Bs[wc + nt * 16 + l15][ks + quad * 8];
            #pragma unroll
            for (int mt = 0; mt < 4; ++mt)
                #pragma unroll
                for (int nt = 0; nt < 2; ++nt)
                    acc[mt][nt] = __builtin_amdgcn_mfma_f32_16x16x32_bf16(
                        af[mt], bfr[nt], acc[mt][nt], 0, 0, 0);
        }
        __syncthreads();
    }

    #pragma unroll
    for (int nt = 0; nt < 2; ++nt) {
        const int c = n0 + wc + nt * 16 + l15;
        const float bv = bias[c];
        #pragma unroll
        for (int mt = 0; mt < 4; ++mt)
            #pragma unroll
            for (int i = 0; i < 4; ++i) {
                const int m = m0 + wr + mt * 16 + quad * 4 + i;
                const float v = acc[mt][nt][i] + bv;
                if (MODE == 0) {
                    ((float*)outv)[(size_t)m * Dn + c] = v;
                } else {
                    const int b = m >> 11, s = m & (Sn - 1);
                    const int h = c >> 6, hd = c & 63;
                    if (MODE == 1)
                        ((bf16*)outv)[(((size_t)(b * Hn + h) * Sn) + s) * HDn + hd] = (bf16)v;
                    else
                        ((bf16*)outv)[(((size_t)(b * Hn + h) * HDn) + hd) * Sn + s] = (bf16)v;
                }
            }
    }
}

// ---------------------------------------------------------------------------
// Flash attention, bf16 MFMA — BARRIER-FREE.
// Q,K: [bh][s][hd]; Vt: [bh][hd][s]. Block = (bh, 64-query tile), 4 waves;
// wave w owns q-rows w*16..w*16+15 and runs fully independently:
//  - Q fragments held in registers (loaded once, global->VGPR)
//  - K / V fragments loaded per chunk directly global->VGPR (L2-resident)
//  - log2-domain online softmax (scale*log2e folded into mod coefficient)
//  - P relayout C->A via wave-local LDS rows (no cross-wave sharing => no
//    __syncthreads anywhere in the K-loop)
// ---------------------------------------------------------------------------
__global__ __launch_bounds__(256) void attn_mfma_k(
    const bf16* __restrict__ Qb, const bf16* __restrict__ Kb,
    const bf16* __restrict__ Vtb, const int* __restrict__ kpm,
    const float* __restrict__ mod, bf16* __restrict__ att)
{
    __shared__ __align__(16) bf16 Ps[64][72];

    const int tid  = threadIdx.x;
    const int w    = tid >> 6;
    const int lane = tid & 63;
    const int quad = lane >> 4;
    const int l15  = lane & 15;
    const int bh   = blockIdx.x;
    const int b    = bh >> 4;
    const int h    = bh & 15;
    const int q0   = blockIdx.y * 64;
    const size_t base = (size_t)bh * Sn * HDn;

    // Q fragments in registers: A[m=l15][k=quad*8+j], rows q0+w*16+l15
    const bf16* qrow = Qb + base + (size_t)(q0 + w * 16 + l15) * HDn;
    const bf16x8 qf0 = *(const bf16x8*)(qrow + quad * 8);
    const bf16x8 qf1 = *(const bf16x8*)(qrow + 32 + quad * 8);

    bool qmask[4];
    #pragma unroll
    for (int i = 0; i < 4; ++i)
        qmask[i] = kpm[(size_t)b * Sn + q0 + w * 16 + quad * 4 + i] != 0;

    // mod row base for this lane's C-layout rows (row i adds i*Sn)
    const float* modrow = mod + ((size_t)b * Sn + q0 + w * 16 + quad * 4) * Sn;
    constexpr float C_SCALE = 0.18033688011112042f;  // 0.125 * log2(e)

    float m2[4] = {-1e30f, -1e30f, -1e30f, -1e30f};
    float l_r[4] = {};
    f32x4 O[4]   = {};

    for (int k0 = 0; k0 < Sn; k0 += 64) {
        // K fragments: B[k=hd][n=key] = K[key][hd]
        bf16x8 kf[4][2];
        #pragma unroll
        for (int ct = 0; ct < 4; ++ct) {
            const bf16* krow = Kb + base + (size_t)(k0 + ct * 16 + l15) * HDn;
            kf[ct][0] = *(const bf16x8*)(krow + quad * 8);
            kf[ct][1] = *(const bf16x8*)(krow + 32 + quad * 8);
        }
        // modifier (pre-scaled to log2 domain)
        float mo[4][4];
        #pragma unroll
        for (int ct = 0; ct < 4; ++ct)
            #pragma unroll
            for (int i = 0; i < 4; ++i)
                mo[ct][i] = modrow[(size_t)i * Sn + k0 + ct * 16 + l15] * C_SCALE;

        // QK^T -> log2-domain energies (C-layout: row=quad*4+i, col=ct*16+l15)
        float e[4][4];
        #pragma unroll
        for (int ct = 0; ct < 4; ++ct) {
            f32x4 s = {};
            s = __builtin_amdgcn_mfma_f32_16x16x32_bf16(qf0, kf[ct][0], s, 0, 0, 0);
            s = __builtin_amdgcn_mfma_f32_16x16x32_bf16(qf1, kf[ct][1], s, 0, 0, 0);
            #pragma unroll
            for (int i = 0; i < 4; ++i)
                e[ct][i] = qmask[i] ? -1e10f : s[i] * mo[ct][i];
        }

        // V fragments (issue early; independent of softmax):
        // B[k=key][n=hd] = Vt[hd][key]
        bf16x8 vf[4][2];
        #pragma unroll
        for (int ct = 0; ct < 4; ++ct) {
            const bf16* vrow = Vtb + base + (size_t)(ct * 16 + l15) * Sn + k0;
            vf[ct][0] = *(const bf16x8*)(vrow + quad * 8);
            vf[ct][1] = *(const bf16x8*)(vrow + 32 + quad * 8);
        }

        // Online softmax (log2 domain), P -> wave-local LDS rows
        float alpha[4];
        #pragma unroll
        for (int i = 0; i < 4; ++i) {
            float mx = fmaxf(fmaxf(e[0][i], e[1][i]), fmaxf(e[2][i], e[3][i]));
            #pragma unroll
            for (int msk = 1; msk < 16; msk <<= 1)
                mx = fmaxf(mx, __shfl_xor(mx, msk, 16));
            const float mnew = fmaxf(m2[i], mx);
            alpha[i] = exp2f(m2[i] - mnew);
            float rs = 0.0f;
            #pragma unroll
            for (int ct = 0; ct < 4; ++ct) {
                const float p = exp2f(e[ct][i] - mnew);
                const bf16 pb = (bf16)p;
                Ps[w * 16 + quad * 4 + i][ct * 16 + l15] = pb;
                rs += (float)pb;   // numerator-consistent rounding
            }
            #pragma unroll
            for (int msk = 1; msk < 16; msk <<= 1)
                rs += __shfl_xor(rs, msk, 16);
            l_r[i] = l_r[i] * alpha[i] + rs;
            m2[i]  = mnew;
        }

        #pragma unroll
        for (int ct = 0; ct < 4; ++ct)
            #pragma unroll
            for (int i = 0; i < 4; ++i)
                O[ct][i] *= alpha[i];

        // P fragments (same wave wrote these rows; lgkmcnt orders ds ops)
        const bf16x8 pf0 = *(const bf16x8*)&Ps[w * 16 + l15][quad * 8];
        const bf16x8 pf1 = *(const bf16x8*)&Ps[w * 16 + l15][32 + quad * 8];
        #pragma unroll
        for (int ct = 0; ct < 4; ++ct) {
            O[ct] = __builtin_amdgcn_mfma_f32_16x16x32_bf16(pf0, vf[ct][0], O[ct], 0, 0, 0);
            O[ct] = __builtin_amdgcn_mfma_f32_16x16x32_bf16(pf1, vf[ct][1], O[ct], 0, 0, 0);
        }
    }

    float inv[4];
    #pragma unroll
    for (int i = 0; i < 4; ++i) inv[i] = 1.0f / l_r[i];
    #pragma unroll
    for (int ct = 0; ct < 4; ++ct)
        #pragma unroll
        for (int i = 0; i < 4; ++i) {
            const int row = q0 + w * 16 + quad * 4 + i;
            const int col = h * HDn + ct * 16 + l15;
            att[((size_t)b * Sn + row) * Dn + col] = (bf16)(O[ct][i] * inv[i]);
        }
}

// ---------------------------------------------------------------------------
// Launch
// ---------------------------------------------------------------------------
extern "C" void kernel_launch(void* const* d_in, const int* in_sizes, int n_in,
                              void* d_out, int out_size, void* d_ws, size_t ws_size,
                              hipStream_t stream) {
    const float* x   = (const float*)d_in[0];
    const int*   kpm = (const int*)d_in[1];
    const float* mod = (const float*)d_in[2];
    const float* Wq  = (const float*)d_in[3];
    const float* bq  = (const float*)d_in[4];
    const float* Wk  = (const float*)d_in[5];
    const float* bk  = (const float*)d_in[6];
    const float* Wv  = (const float*)d_in[7];
    const float* bv  = (const float*)d_in[8];
    const float* Wo  = (const float*)d_in[9];
    const float* bo  = (const float*)d_in[10];
    float* out = (float*)d_out;

    bf16* ws = (bf16*)d_ws;
    const size_t sz = (size_t)Bn * Sn * Dn;   // 8388608
    const size_t wz = (size_t)Dn * Dn;        // 1048576
    bf16* xb   = ws;
    bf16* qb   = ws + sz;
    bf16* kb   = ws + 2 * sz;
    bf16* vtb  = ws + 3 * sz;
    bf16* attb = ws + 4 * sz;
    bf16* wqt  = ws + 5 * sz;
    bf16* wkt  = wqt + wz;
    bf16* wvt  = wkt + wz;
    bf16* wot  = wvt + wz;

    conv_f32_bf16_k<<<(int)(sz / 1024), 256, 0, stream>>>(x, xb, (int)sz);
    conv_wt_k<<<dim3(16, 16, 4), 256, 0, stream>>>(Wq, Wk, Wv, Wo, wqt, wkt, wvt, wot);

    const dim3 gemm_grid(64, 16);   // (8192/128, 1024/64)
    gemm_bf16_k<1><<<gemm_grid, 256, 0, stream>>>(xb, wqt, bq, qb);
    gemm_bf16_k<1><<<gemm_grid, 256, 0, stream>>>(xb, wkt, bk, kb);
    gemm_bf16_k<2><<<gemm_grid, 256, 0, stream>>>(xb, wvt, bv, vtb);

    attn_mfma_k<<<dim3(Bn * Hn, Sn / 64), 256, 0, stream>>>(qb, kb, vtb, kpm, mod, attb);

    gemm_bf16_k<0><<<gemm_grid, 256, 0, stream>>>(attb, wot, bo, out);
}

// Round 5
// 729.874 us; speedup vs baseline: 1.0110x; 1.0110x over previous
//
#include <hip/hip_runtime.h>
#include <cstddef>

// Problem constants: B=4, S=2048, D=1024, H=16, HD=64
constexpr int Bn  = 4;
constexpr int Sn  = 2048;
constexpr int Dn  = 1024;
constexpr int Hn  = 16;
constexpr int HDn = 64;

typedef __bf16 bf16;
typedef __attribute__((ext_vector_type(8))) __bf16 bf16x8;
typedef __attribute__((ext_vector_type(4))) float  f32x4;

// ---------------------------------------------------------------------------
// Elementwise fp32 -> bf16 (x staging)
// ---------------------------------------------------------------------------
__global__ __launch_bounds__(256) void conv_f32_bf16_k(
    const float* __restrict__ in, bf16* __restrict__ out, int n)
{
    int i = (blockIdx.x * 256 + threadIdx.x) * 4;
    if (i + 3 < n) {
        float4 v = *(const float4*)(in + i);
        bf16 o[4] = {(bf16)v.x, (bf16)v.y, (bf16)v.z, (bf16)v.w};
        *(ulong1*)(out + i) = *(ulong1*)o;  // 8B store
    }
}

// ---------------------------------------------------------------------------
// Weight transpose + convert: W[k][n] fp32 -> Wt[n][k] bf16. 64x64 tiles.
// ---------------------------------------------------------------------------
__global__ __launch_bounds__(256) void conv_wt_k(
    const float* __restrict__ w0, const float* __restrict__ w1,
    const float* __restrict__ w2, const float* __restrict__ w3,
    bf16* __restrict__ o0, bf16* __restrict__ o1,
    bf16* __restrict__ o2, bf16* __restrict__ o3)
{
    const float* W = (blockIdx.z == 0) ? w0 : (blockIdx.z == 1) ? w1
                   : (blockIdx.z == 2) ? w2 : w3;
    bf16* O = (blockIdx.z == 0) ? o0 : (blockIdx.z == 1) ? o1
            : (blockIdx.z == 2) ? o2 : o3;
    __shared__ float t[64][65];
    const int tid = threadIdx.x;
    const int k0 = blockIdx.x * 64;
    const int n0 = blockIdx.y * 64;
    #pragma unroll
    for (int p = 0; p < 16; ++p) {
        const int idx = p * 256 + tid;
        const int r = idx >> 6, c = idx & 63;
        t[r][c] = W[(size_t)(k0 + r) * Dn + n0 + c];
    }
    __syncthreads();
    #pragma unroll
    for (int p = 0; p < 16; ++p) {
        const int idx = p * 256 + tid;
        const int r = idx >> 6, c = idx & 63;
        O[(size_t)(n0 + r) * Dn + k0 + c] = (bf16)t[c][r];
    }
}

// ---------------------------------------------------------------------------
// bf16 MFMA GEMM: out = A(8192 x 1024) @ Bt^T + bias, Bt is [N][K] bf16.
// Tile 128x64, 256 thr / 4 waves (2x2), each wave 64x32 (4x2 of 16x16 frags).
// MODE 0: fp32 out [M][N];  MODE 1: bf16 out [b,h,s,hd];  MODE 2: bf16 [b,h,hd,s]
// QS: post-scale output by 0.125*log2(e)  (Q projection only — folds the
//     attention scale + log2-domain conversion into the GEMM epilogue)
// ---------------------------------------------------------------------------
template <int MODE, bool QS>
__global__ __launch_bounds__(256) void gemm_bf16_k(
    const bf16* __restrict__ A, const bf16* __restrict__ Bt,
    const float* __restrict__ bias, void* __restrict__ outv)
{
    __shared__ __align__(16) bf16 As[128][72];
    __shared__ __align__(16) bf16 Bs[64][72];

    const int tid  = threadIdx.x;
    const int w    = tid >> 6;
    const int lane = tid & 63;
    const int quad = lane >> 4;
    const int l15  = lane & 15;
    const int wr   = (w & 1) * 64;
    const int wc   = (w >> 1) * 32;
    const int m0   = blockIdx.x * 128;
    const int n0   = blockIdx.y * 64;

    f32x4 acc[4][2] = {};

    for (int k0 = 0; k0 < Dn; k0 += 64) {
        #pragma unroll
        for (int p = 0; p < 4; ++p) {
            const int idx = p * 256 + tid;
            const int r = idx >> 3, off = (idx & 7) * 8;
            *(bf16x8*)&As[r][off] =
                *(const bf16x8*)(A + (size_t)(m0 + r) * Dn + k0 + off);
        }
        #pragma unroll
        for (int p = 0; p < 2; ++p) {
            const int idx = p * 256 + tid;
            const int r = idx >> 3, off = (idx & 7) * 8;
            *(bf16x8*)&Bs[r][off] =
                *(const bf16x8*)(Bt + (size_t)(n0 + r) * Dn + k0 + off);
        }
        __syncthreads();
        #pragma unroll
        for (int ks = 0; ks < 64; ks += 32) {
            bf16x8 af[4], bfr[2];
            #pragma unroll
            for (int mt = 0; mt < 4; ++mt)
                af[mt] = *(const bf16x8*)&As[wr + mt * 16 + l15][ks + quad * 8];
            #pragma unroll
            for (int nt = 0; nt < 2; ++nt)
                bfr[nt] = *(const bf16x8*)&Bs[wc + nt * 16 + l15][ks + quad * 8];
            #pragma unroll
            for (int mt = 0; mt < 4; ++mt)
                #pragma unroll
                for (int nt = 0; nt < 2; ++nt)
                    acc[mt][nt] = __builtin_amdgcn_mfma_f32_16x16x32_bf16(
                        af[mt], bfr[nt], acc[mt][nt], 0, 0, 0);
        }
        __syncthreads();
    }

    #pragma unroll
    for (int nt = 0; nt < 2; ++nt) {
        const int c = n0 + wc + nt * 16 + l15;
        const float bv = bias[c];
        #pragma unroll
        for (int mt = 0; mt < 4; ++mt)
            #pragma unroll
            for (int i = 0; i < 4; ++i) {
                const int m = m0 + wr + mt * 16 + quad * 4 + i;
                float v = acc[mt][nt][i] + bv;
                if (QS) v *= 0.18033688011112042f;   // 0.125 * log2(e)
                if (MODE == 0) {
                    ((float*)outv)[(size_t)m * Dn + c] = v;
                } else {
                    const int b = m >> 11, s = m & (Sn - 1);
                    const int h = c >> 6, hd = c & 63;
                    if (MODE == 1)
                        ((bf16*)outv)[(((size_t)(b * Hn + h) * Sn) + s) * HDn + hd] = (bf16)v;
                    else
                        ((bf16*)outv)[(((size_t)(b * Hn + h) * HDn) + hd) * Sn + s] = (bf16)v;
                }
            }
    }
}

// ---------------------------------------------------------------------------
// Flash attention, bf16 MFMA — barrier-free, STATIC-MAX softmax, double-
// buffered K+mod register prefetch.
//   p = exp2( s*mo - 16 )   (s pre-scaled by 0.125*log2e in the Q GEMM;
//   softmax shift-invariance makes the fixed shift exact; masked rows use
//   arg = -16 -> uniform weights -> mean(V), matching the reference).
// No shuffles / no rescaling in the K-loop; per-lane l partials reduced once
// at the end. Q,K: [bh][s][hd]; Vt: [bh][hd][s].
// ---------------------------------------------------------------------------
__global__ __launch_bounds__(256) void attn_mfma_k(
    const bf16* __restrict__ Qb, const bf16* __restrict__ Kb,
    const bf16* __restrict__ Vtb, const int* __restrict__ kpm,
    const float* __restrict__ mod, bf16* __restrict__ att)
{
    __shared__ __align__(16) bf16 Ps[64][72];

    const int tid  = threadIdx.x;
    const int w    = tid >> 6;
    const int lane = tid & 63;
    const int quad = lane >> 4;
    const int l15  = lane & 15;
    const int bh   = blockIdx.x;
    const int b    = bh >> 4;
    const int h    = bh & 15;
    const int q0   = blockIdx.y * 64;
    const size_t base = (size_t)bh * Sn * HDn;

    // Q fragments in registers: A[m=l15][k=quad*8+j]
    const bf16* qrow = Qb + base + (size_t)(q0 + w * 16 + l15) * HDn;
    const bf16x8 qf0 = *(const bf16x8*)(qrow + quad * 8);
    const bf16x8 qf1 = *(const bf16x8*)(qrow + 32 + quad * 8);

    bool qmask[4];
    #pragma unroll
    for (int i = 0; i < 4; ++i)
        qmask[i] = kpm[(size_t)b * Sn + q0 + w * 16 + quad * 4 + i] != 0;

    const float* modrow = mod + ((size_t)b * Sn + q0 + w * 16 + quad * 4) * Sn;
    constexpr float SMAX = 16.0f;

    float l_r[4] = {};
    f32x4 O[4]   = {};

    bf16x8 kfA[4][2], kfB[4][2];
    float  moA[4][4], moB[4][4];

    // chunk-0 loads into buffer A
    #pragma unroll
    for (int ct = 0; ct < 4; ++ct) {
        const bf16* krow = Kb + base + (size_t)(ct * 16 + l15) * HDn;
        kfA[ct][0] = *(const bf16x8*)(krow + quad * 8);
        kfA[ct][1] = *(const bf16x8*)(krow + 32 + quad * 8);
        #pragma unroll
        for (int i = 0; i < 4; ++i)
            moA[ct][i] = modrow[(size_t)i * Sn + ct * 16 + l15];
    }

    auto body = [&](int it, bf16x8 (&kfc)[4][2], float (&moc)[4][4],
                    bf16x8 (&kfn)[4][2], float (&mon)[4][4]) {
        const int k0 = it * 64;
        // Prefetch chunk it+1 into the other buffer (uniform branch).
        if (it < 31) {
            #pragma unroll
            for (int ct = 0; ct < 4; ++ct) {
                const bf16* krow = Kb + base + (size_t)(k0 + 64 + ct * 16 + l15) * HDn;
                kfn[ct][0] = *(const bf16x8*)(krow + quad * 8);
                kfn[ct][1] = *(const bf16x8*)(krow + 32 + quad * 8);
                #pragma unroll
                for (int i = 0; i < 4; ++i)
                    mon[ct][i] = modrow[(size_t)i * Sn + k0 + 64 + ct * 16 + l15];
            }
        }
        // V fragments for this chunk (issued before softmax; overlaps it).
        bf16x8 vf[4][2];
        #pragma unroll
        for (int ct = 0; ct < 4; ++ct) {
            const bf16* vrow = Vtb + base + (size_t)(ct * 16 + l15) * Sn + k0;
            vf[ct][0] = *(const bf16x8*)(vrow + quad * 8);
            vf[ct][1] = *(const bf16x8*)(vrow + 32 + quad * 8);
        }
        // QK^T -> p = exp2(s*mo - SMAX); P -> wave-local LDS rows.
        #pragma unroll
        for (int ct = 0; ct < 4; ++ct) {
            f32x4 s = {};
            s = __builtin_amdgcn_mfma_f32_16x16x32_bf16(qf0, kfc[ct][0], s, 0, 0, 0);
            s = __builtin_amdgcn_mfma_f32_16x16x32_bf16(qf1, kfc[ct][1], s, 0, 0, 0);
            #pragma unroll
            for (int i = 0; i < 4; ++i) {
                const float arg = qmask[i] ? -SMAX : fmaf(s[i], moc[ct][i], -SMAX);
                const float p  = exp2f(arg);
                const bf16 pb  = (bf16)p;
                Ps[w * 16 + quad * 4 + i][ct * 16 + l15] = pb;
                l_r[i] += (float)pb;   // numerator-consistent partial sum
            }
        }
        // P fragments (rows this wave wrote; in-order DS pipe per wave).
        const bf16x8 pf0 = *(const bf16x8*)&Ps[w * 16 + l15][quad * 8];
        const bf16x8 pf1 = *(const bf16x8*)&Ps[w * 16 + l15][32 + quad * 8];
        #pragma unroll
        for (int ct = 0; ct < 4; ++ct) {
            O[ct] = __builtin_amdgcn_mfma_f32_16x16x32_bf16(pf0, vf[ct][0], O[ct], 0, 0, 0);
            O[ct] = __builtin_amdgcn_mfma_f32_16x16x32_bf16(pf1, vf[ct][1], O[ct], 0, 0, 0);
        }
    };

    for (int it2 = 0; it2 < 16; ++it2) {
        body(2 * it2,     kfA, moA, kfB, moB);
        body(2 * it2 + 1, kfB, moB, kfA, moA);
    }

    // Final per-row l reduction (once, outside the loop).
    float inv[4];
    #pragma unroll
    for (int i = 0; i < 4; ++i) {
        float rs = l_r[i];
        #pragma unroll
        for (int msk = 1; msk < 16; msk <<= 1)
            rs += __shfl_xor(rs, msk, 16);
        inv[i] = 1.0f / rs;
    }
    #pragma unroll
    for (int ct = 0; ct < 4; ++ct)
        #pragma unroll
        for (int i = 0; i < 4; ++i) {
            const int row = q0 + w * 16 + quad * 4 + i;
            const int col = h * HDn + ct * 16 + l15;
            att[((size_t)b * Sn + row) * Dn + col] = (bf16)(O[ct][i] * inv[i]);
        }
}

// ---------------------------------------------------------------------------
// Launch
// ---------------------------------------------------------------------------
extern "C" void kernel_launch(void* const* d_in, const int* in_sizes, int n_in,
                              void* d_out, int out_size, void* d_ws, size_t ws_size,
                              hipStream_t stream) {
    const float* x   = (const float*)d_in[0];
    const int*   kpm = (const int*)d_in[1];
    const float* mod = (const float*)d_in[2];
    const float* Wq  = (const float*)d_in[3];
    const float* bq  = (const float*)d_in[4];
    const float* Wk  = (const float*)d_in[5];
    const float* bk  = (const float*)d_in[6];
    const float* Wv  = (const float*)d_in[7];
    const float* bv  = (const float*)d_in[8];
    const float* Wo  = (const float*)d_in[9];
    const float* bo  = (const float*)d_in[10];
    float* out = (float*)d_out;

    bf16* ws = (bf16*)d_ws;
    const size_t sz = (size_t)Bn * Sn * Dn;   // 8388608
    const size_t wz = (size_t)Dn * Dn;        // 1048576
    bf16* xb   = ws;
    bf16* qb   = ws + sz;
    bf16* kb   = ws + 2 * sz;
    bf16* vtb  = ws + 3 * sz;
    bf16* attb = ws + 4 * sz;
    bf16* wqt  = ws + 5 * sz;
    bf16* wkt  = wqt + wz;
    bf16* wvt  = wkt + wz;
    bf16* wot  = wvt + wz;

    conv_f32_bf16_k<<<(int)(sz / 1024), 256, 0, stream>>>(x, xb, (int)sz);
    conv_wt_k<<<dim3(16, 16, 4), 256, 0, stream>>>(Wq, Wk, Wv, Wo, wqt, wkt, wvt, wot);

    const dim3 gemm_grid(64, 16);   // (8192/128, 1024/64)
    gemm_bf16_k<1, true ><<<gemm_grid, 256, 0, stream>>>(xb, wqt, bq, qb);   // Q (pre-scaled)
    gemm_bf16_k<1, false><<<gemm_grid, 256, 0, stream>>>(xb, wkt, bk, kb);   // K
    gemm_bf16_k<2, false><<<gemm_grid, 256, 0, stream>>>(xb, wvt, bv, vtb);  // V^T

    attn_mfma_k<<<dim3(Bn * Hn, Sn / 64), 256, 0, stream>>>(qb, kb, vtb, kpm, mod, attb);

    gemm_bf16_k<0, false><<<gemm_grid, 256, 0, stream>>>(attb, wot, bo, out);
}